// Round 2
// baseline (52032.001 us; speedup 1.0000x reference)
//
#include <hip/hip_runtime.h>
#include <math.h>

// Problem dims (fixed by the reference)
namespace {
constexpr int B  = 512;
constexpr int S  = 1024;
constexpr int ID = 64;    // input / output feature dim
constexpr int H  = 512;
constexpr int T  = 256;
constexpr int KC = 32;    // k-chunk
constexpr int PAD = 34;   // even pad: float2-aligned, <=2-way bank conflicts
}

// Init: d_out[b][t][i] = bl[i] (atomicAdd target), y0[b][i] = bl[i], h0 = 0.
__global__ __launch_bounds__(256) void init_kernel(float* __restrict__ out,
                                                   float* __restrict__ y0,
                                                   float* __restrict__ h0,
                                                   const float* __restrict__ bl) {
    const long total_out = (long)B * T * ID;
    const long total_y0  = total_out + (long)B * ID;
    const long total     = total_y0 + (long)B * H;
    for (long idx = (long)blockIdx.x * 256 + threadIdx.x; idx < total;
         idx += (long)gridDim.x * 256) {
        if (idx < total_out)      out[idx] = bl[idx & (ID - 1)];
        else if (idx < total_y0)  y0[idx - total_out] = bl[(idx - total_out) & (ID - 1)];
        else                      h0[idx - total_y0] = 0.f;
    }
}

// One GRU cell step for the whole batch.
//   gi = xin @ Wi.T + bi ; gh = h_in @ Wh.T + bh  (gates ordered r,z,n)
//   r = sig(gi_r+gh_r); z = sig(gi_z+gh_z); n = tanh(gi_n + r*gh_n)
//   h_out = (1-z)*n + z*h_in
// Tiles: 32 (b) x 32 (j) per block, 256 blocks (1/CU), 256 threads, 2x2/thread.
__global__ __launch_bounds__(256) void gru_step(
    const float* __restrict__ xin, int xin_stride,   // [B, ID] rows at xin_stride
    const float* __restrict__ h_in,                  // [B, H]
    const float* __restrict__ Wi,                    // [3H, ID]
    const float* __restrict__ Wh,                    // [3H, H]
    const float* __restrict__ bi,                    // [3H]
    const float* __restrict__ bh,                    // [3H]
    float* __restrict__ h_out)                       // [B, H]
{
    __shared__ float ws[3][KC][PAD];  // [gate][k][j]  (transposed)
    __shared__ float hs[KC][PAD];     // [k][b]        (transposed)

    const int tid = threadIdx.x;
    const int j0 = blockIdx.x * 32;
    const int b0 = blockIdx.y * 32;

    // output mapping: 2 (b) x 2 (j) per thread
    const int tx = tid & 15;        // j-pair index
    const int ty = tid >> 4;        // b-pair index
    const int jj0 = tx * 2;
    const int bb0 = ty * 2;

    float acc_r[2][2]  = {{0.f,0.f},{0.f,0.f}};
    float acc_z[2][2]  = {{0.f,0.f},{0.f,0.f}};
    float acc_nh[2][2] = {{0.f,0.f},{0.f,0.f}};  // Wh·h part of n-gate
    float acc_nx[2][2] = {{0.f,0.f},{0.f,0.f}};  // Wi·x part of n-gate

    // staging mapping: c = k within chunk (coalesced), r0 = row group
    const int c  = tid & 31;
    const int r0 = tid >> 5;        // 0..7

    constexpr int NCH_H = H / KC;   // 16 chunks over hidden
    constexpr int NCH_X = ID / KC;  // 2 chunks over input

    for (int ch = 0; ch < NCH_H + NCH_X; ++ch) {
        const bool isH = (ch < NCH_H);
        const float* src = isH ? h_in : xin;
        const float* W   = isH ? Wh : Wi;
        const int kst = isH ? H : ID;             // weight row stride
        const int sst = isH ? H : xin_stride;     // activation row stride
        const int k0  = isH ? ch * KC : (ch - NCH_H) * KC;

        __syncthreads();
        // stage activations transposed: hs[k][b]
        #pragma unroll
        for (int q = 0; q < 4; ++q) {
            const int r = r0 + q * 8;
            hs[c][r] = src[(long)(b0 + r) * sst + k0 + c];
        }
        // stage weights transposed: ws[g][k][j]
        #pragma unroll
        for (int g = 0; g < 3; ++g) {
            #pragma unroll
            for (int q = 0; q < 4; ++q) {
                const int r = r0 + q * 8;
                ws[g][c][r] = W[(long)(g * H + j0 + r) * kst + k0 + c];
            }
        }
        __syncthreads();

        if (isH) {
            #pragma unroll
            for (int kk = 0; kk < KC; ++kk) {
                const float2 hv = *(const float2*)&hs[kk][bb0];
                const float2 wr = *(const float2*)&ws[0][kk][jj0];
                const float2 wz = *(const float2*)&ws[1][kk][jj0];
                const float2 wn = *(const float2*)&ws[2][kk][jj0];
                acc_r[0][0] += hv.x * wr.x;  acc_r[0][1] += hv.x * wr.y;
                acc_r[1][0] += hv.y * wr.x;  acc_r[1][1] += hv.y * wr.y;
                acc_z[0][0] += hv.x * wz.x;  acc_z[0][1] += hv.x * wz.y;
                acc_z[1][0] += hv.y * wz.x;  acc_z[1][1] += hv.y * wz.y;
                acc_nh[0][0] += hv.x * wn.x; acc_nh[0][1] += hv.x * wn.y;
                acc_nh[1][0] += hv.y * wn.x; acc_nh[1][1] += hv.y * wn.y;
            }
        } else {
            #pragma unroll
            for (int kk = 0; kk < KC; ++kk) {
                const float2 hv = *(const float2*)&hs[kk][bb0];
                const float2 wr = *(const float2*)&ws[0][kk][jj0];
                const float2 wz = *(const float2*)&ws[1][kk][jj0];
                const float2 wn = *(const float2*)&ws[2][kk][jj0];
                acc_r[0][0] += hv.x * wr.x;  acc_r[0][1] += hv.x * wr.y;
                acc_r[1][0] += hv.y * wr.x;  acc_r[1][1] += hv.y * wr.y;
                acc_z[0][0] += hv.x * wz.x;  acc_z[0][1] += hv.x * wz.y;
                acc_z[1][0] += hv.y * wz.x;  acc_z[1][1] += hv.y * wz.y;
                acc_nx[0][0] += hv.x * wn.x; acc_nx[0][1] += hv.x * wn.y;
                acc_nx[1][0] += hv.y * wn.x; acc_nx[1][1] += hv.y * wn.y;
            }
        }
    }

    // epilogue: gate math + state update
    #pragma unroll
    for (int jj = 0; jj < 2; ++jj) {
        const int j = j0 + jj0 + jj;
        const float bir = bi[j]         + bh[j];
        const float biz = bi[H + j]     + bh[H + j];
        const float bin = bi[2 * H + j];
        const float bhn = bh[2 * H + j];
        #pragma unroll
        for (int bb = 0; bb < 2; ++bb) {
            const int b = b0 + bb0 + bb;
            const float rr = acc_r[bb][jj] + bir;
            const float zz = acc_z[bb][jj] + biz;
            const float rg = 1.f / (1.f + expf(-rr));
            const float zg = 1.f / (1.f + expf(-zz));
            const float nn = tanhf(acc_nx[bb][jj] + bin + rg * (acc_nh[bb][jj] + bhn));
            h_out[(long)b * H + j] = (1.f - zg) * nn + zg * h_in[(long)b * H + j];
        }
    }
}

// y[b][i] (+)= sum_k h[b][k] * Wl[i][k], split-K(4), atomicAdd into a
// destination pre-initialized with bl. dst row stride in floats.
__global__ __launch_bounds__(64) void linear_y(
    const float* __restrict__ h,    // [B, H]
    const float* __restrict__ Wl,   // [ID, H]
    float* __restrict__ dst, int dst_stride)
{
    const int b = blockIdx.x >> 2;
    const int s = blockIdx.x & 3;
    const int i = threadIdx.x;      // 0..63
    const float4* h4 = (const float4*)(h  + (long)b * H + s * 128);
    const float4* w4 = (const float4*)(Wl + (long)i * H + s * 128);
    float acc = 0.f;
    #pragma unroll
    for (int k = 0; k < 32; ++k) {
        const float4 a = h4[k];
        const float4 w = w4[k];
        acc += a.x * w.x + a.y * w.y + a.z * w.z + a.w * w.w;
    }
    atomicAdd(&dst[(long)b * dst_stride + i], acc);
}

extern "C" void kernel_launch(void* const* d_in, const int* in_sizes, int n_in,
                              void* d_out, int out_size, void* d_ws, size_t ws_size,
                              hipStream_t stream) {
    const float* x  = (const float*)d_in[0];   // [B,S,ID]
    const float* Wi = (const float*)d_in[1];   // [3H,ID]
    const float* Wh = (const float*)d_in[2];   // [3H,H]
    const float* bi = (const float*)d_in[3];   // [3H]
    const float* bh = (const float*)d_in[4];   // [3H]
    const float* Wl = (const float*)d_in[5];   // [ID,H]
    const float* bl = (const float*)d_in[6];   // [ID]
    float* out = (float*)d_out;                // [B,T,ID]

    // workspace: h ping/pong (1 MB each) + y0 buffer (128 KB) = ~2.2 MB
    float* hA = (float*)d_ws;
    float* hB = hA + (long)B * H;
    float* y0 = hB + (long)B * H;

    init_kernel<<<2048, 256, 0, stream>>>(out, y0, hA, bl);

    const dim3 grid(H / 32, B / 32);   // 16 x 16 = 256 blocks

    // ---- encoder ----
    const float* hin = hA;
    float* hout = hB;
    for (int t = 0; t < S; ++t) {
        gru_step<<<grid, 256, 0, stream>>>(x + (long)t * ID, S * ID,
                                           hin, Wi, Wh, bi, bh, hout);
        const float* tmp = hout; hout = (float*)hin; hin = tmp;
    }
    // hin == h_n

    // ---- y0 = h_n @ Wl.T + bl (bl pre-loaded by init) ----
    linear_y<<<B * 4, 64, 0, stream>>>(hin, Wl, y0, ID);

    // ---- decoder ----
    const float* inp = y0;
    int instride = ID;
    for (int t = 0; t < T; ++t) {
        gru_step<<<grid, 256, 0, stream>>>(inp, instride,
                                           hin, Wi, Wh, bi, bh, hout);
        const float* tmp = hout; hout = (float*)hin; hin = tmp;
        // y_t = h @ Wl.T + bl -> straight into d_out slice t (pre-init'd to bl)
        linear_y<<<B * 4, 64, 0, stream>>>(hin, Wl, out + (long)t * ID, T * ID);
        inp = out + (long)t * ID;   // decoder feeds its own output back
        instride = T * ID;
    }
}

// Round 3
// 14139.070 us; speedup vs baseline: 3.6800x; 3.6800x over previous
//
#include <hip/hip_runtime.h>
#include <hip/hip_bf16.h>
#include <math.h>

// Problem dims (fixed by the reference)
namespace {
constexpr int B  = 512;
constexpr int S  = 1024;
constexpr int ID = 64;    // input / output feature dim
constexpr int H  = 512;
constexpr int T  = 256;
constexpr int NKT = 18;   // K-chunks of 32: 16 over h (K=512) + 2 over x (K=64)
}

using short8  = __attribute__((ext_vector_type(8))) short;
using float4v = __attribute__((ext_vector_type(4))) float;

// ---- helpers ----------------------------------------------------------------
__device__ inline ushort bfbits(float x) {
    union { __hip_bfloat16 h; ushort u; } cv;
    cv.h = __float2bfloat16(x);   // RNE
    return cv.u;
}

// Load 8 consecutive fp32 and convert to a bf16 A-fragment half-row.
__device__ inline short8 cvt8(const float* __restrict__ p) {
    const float4v f0 = *(const float4v*)p;
    const float4v f1 = *(const float4v*)(p + 4);
    short8 a;
    a[0] = (short)bfbits(f0[0]); a[1] = (short)bfbits(f0[1]);
    a[2] = (short)bfbits(f0[2]); a[3] = (short)bfbits(f0[3]);
    a[4] = (short)bfbits(f1[0]); a[5] = (short)bfbits(f1[1]);
    a[6] = (short)bfbits(f1[2]); a[7] = (short)bfbits(f1[3]);
    return a;
}

// ---- one-time prep ----------------------------------------------------------

// Init: d_out[b][t][i] = bl[i] (atomicAdd target), y0[b][i] = bl[i], h0 = 0.
__global__ __launch_bounds__(256) void init_kernel(float* __restrict__ out,
                                                   float* __restrict__ y0,
                                                   float* __restrict__ h0,
                                                   const float* __restrict__ bl) {
    const long total_out = (long)B * T * ID;
    const long total_y0  = total_out + (long)B * ID;
    const long total     = total_y0 + (long)B * H;
    for (long idx = (long)blockIdx.x * 256 + threadIdx.x; idx < total;
         idx += (long)gridDim.x * 256) {
        if (idx < total_out)      out[idx] = bl[idx & (ID - 1)];
        else if (idx < total_y0)  y0[idx - total_out] = bl[(idx - total_out) & (ID - 1)];
        else                      h0[idx - total_y0] = 0.f;
    }
}

// Swizzle [Wh | Wi] (fp32) into MFMA-native bf16 B-fragments.
// Virtual K = 576 = [h: 0..511 | x: 512..575], chunks of 32.
// Fragment block (g, jt, kt): 64 lanes x 16B; lane l, elem i holds
//   W[g*512 + jt*16 + (l&15)][ kt*32 + (l>>4)*8 + i ]   (bf16)
// so a wave's global_load_dwordx4 at (lane*16) is the exact B operand of
// v_mfma_f32_16x16x32_bf16 (B[k][n]: n = lane&15, k = (lane>>4)*8 + i).
__global__ __launch_bounds__(256) void prep_swizzle(const float* __restrict__ Wh,
                                                    const float* __restrict__ Wi,
                                                    ushort* __restrict__ Bs) {
    const int t = blockIdx.x * 256 + threadIdx.x;
    constexpr int TOT = 3 * 32 * NKT * 64;     // 110592 lanes-worth
    if (t >= TOT) return;
    const int l   = t & 63;
    int rest      = t >> 6;
    const int kt  = rest % NKT;  rest /= NKT;
    const int jt  = rest & 31;
    const int g   = rest >> 5;

    const int j  = jt * 16 + (l & 15);
    const int kb = kt * 32 + ((l >> 4) << 3);  // virtual-k base for this lane

    ushort v[8];
    if (kt < 16) {
        const float* src = Wh + (long)(g * H + j) * H + kb;
        #pragma unroll
        for (int i = 0; i < 8; ++i) v[i] = bfbits(src[i]);
    } else {
        const float* src = Wi + (long)(g * H + j) * ID + (kb - H);
        #pragma unroll
        for (int i = 0; i < 8; ++i) v[i] = bfbits(src[i]);
    }
    ushort* dst = Bs + (size_t)t * 8;          // == block_idx*512 + l*8
    *(short8*)dst = *(short8*)v;
}

// ---- the sequential GRU step (bf16 MFMA, LDS-free) -------------------------
// Grid: 256 blocks x 256 thr. Block = 16 b-rows x 64 gate-j cols; each of the
// 4 waves owns one 16x16 (b x j) tile across all 3 gates.
__global__ __launch_bounds__(256) void gru_step_mfma(
    const float* __restrict__ xin, long xstride,   // [B, ID] rows
    const float* __restrict__ h_in,                // [B, H] fp32
    const ushort* __restrict__ Bs,                 // swizzled weights
    const float* __restrict__ bi,
    const float* __restrict__ bh,
    float* __restrict__ h_out)                     // [B, H] fp32
{
    const int tid = threadIdx.x;
    const int w = tid >> 6;
    const int l = tid & 63;
    const int btile = blockIdx.x & 31;             // 32 tiles of 16 b-rows
    const int jt    = ((blockIdx.x >> 5) << 2) + w;  // 0..31, 16 j-cols each
    const int b0 = btile << 4;
    const int arow = b0 + (l & 15);
    const int kb = (l >> 4) << 3;                  // 0,8,16,24

    float4v acc_r{0.f,0.f,0.f,0.f}, acc_z{0.f,0.f,0.f,0.f};
    float4v acc_nh{0.f,0.f,0.f,0.f}, acc_nx{0.f,0.f,0.f,0.f};

    constexpr size_t GSTEP = (size_t)32 * NKT * 512;   // ushorts per gate
    const ushort* bsw = Bs + (size_t)jt * NKT * 512 + ((size_t)l << 3);

    // h part: virtual k 0..511
    const float* ah = h_in + (size_t)arow * H + kb;
    #pragma unroll
    for (int kt = 0; kt < 16; ++kt) {
        const short8 a  = cvt8(ah + kt * 32);
        const short8 br = *(const short8*)(bsw + ((size_t)kt << 9));
        const short8 bz = *(const short8*)(bsw + GSTEP + ((size_t)kt << 9));
        const short8 bn = *(const short8*)(bsw + 2 * GSTEP + ((size_t)kt << 9));
        acc_r  = __builtin_amdgcn_mfma_f32_16x16x32_bf16(a, br, acc_r, 0, 0, 0);
        acc_z  = __builtin_amdgcn_mfma_f32_16x16x32_bf16(a, bz, acc_z, 0, 0, 0);
        acc_nh = __builtin_amdgcn_mfma_f32_16x16x32_bf16(a, bn, acc_nh, 0, 0, 0);
    }
    // x part: virtual k 512..575
    const float* ax = xin + (size_t)arow * xstride + kb;
    #pragma unroll
    for (int kt = 16; kt < 18; ++kt) {
        const short8 a  = cvt8(ax + (kt - 16) * 32);
        const short8 br = *(const short8*)(bsw + ((size_t)kt << 9));
        const short8 bz = *(const short8*)(bsw + GSTEP + ((size_t)kt << 9));
        const short8 bn = *(const short8*)(bsw + 2 * GSTEP + ((size_t)kt << 9));
        acc_r  = __builtin_amdgcn_mfma_f32_16x16x32_bf16(a, br, acc_r, 0, 0, 0);
        acc_z  = __builtin_amdgcn_mfma_f32_16x16x32_bf16(a, bz, acc_z, 0, 0, 0);
        acc_nx = __builtin_amdgcn_mfma_f32_16x16x32_bf16(a, bn, acc_nx, 0, 0, 0);
    }

    // epilogue: gate math + state update
    const int j = (jt << 4) + (l & 15);
    const float bir = bi[j]         + bh[j];
    const float biz = bi[H + j]     + bh[H + j];
    const float bin = bi[2 * H + j];
    const float bhn = bh[2 * H + j];
    #pragma unroll
    for (int c = 0; c < 4; ++c) {
        const int b = b0 + ((l >> 4) << 2) + c;   // C/D row = (lane>>4)*4 + reg
        const float r = 1.f / (1.f + expf(-(acc_r[c] + bir)));
        const float z = 1.f / (1.f + expf(-(acc_z[c] + biz)));
        const float n = tanhf(acc_nx[c] + bin + r * (acc_nh[c] + bhn));
        h_out[(size_t)b * H + j] = (1.f - z) * n + z * h_in[(size_t)b * H + j];
    }
}

// y[b][i] (+)= sum_k h[b][k] * Wl[i][k], split-K(4), atomicAdd into a
// destination pre-initialized with bl. dst row stride in floats.
__global__ __launch_bounds__(64) void linear_y(
    const float* __restrict__ h,    // [B, H] fp32
    const float* __restrict__ Wl,   // [ID, H]
    float* __restrict__ dst, int dst_stride)
{
    const int b = blockIdx.x >> 2;
    const int s = blockIdx.x & 3;
    const int i = threadIdx.x;      // 0..63
    const float4* h4 = (const float4*)(h  + (long)b * H + s * 128);
    const float4* w4 = (const float4*)(Wl + (long)i * H + s * 128);
    float acc = 0.f;
    #pragma unroll
    for (int k = 0; k < 32; ++k) {
        const float4 a = h4[k];
        const float4 w = w4[k];
        acc += a.x * w.x + a.y * w.y + a.z * w.z + a.w * w.w;
    }
    atomicAdd(&dst[(long)b * dst_stride + i], acc);
}

extern "C" void kernel_launch(void* const* d_in, const int* in_sizes, int n_in,
                              void* d_out, int out_size, void* d_ws, size_t ws_size,
                              hipStream_t stream) {
    const float* x  = (const float*)d_in[0];   // [B,S,ID]
    const float* Wi = (const float*)d_in[1];   // [3H,ID]
    const float* Wh = (const float*)d_in[2];   // [3H,H]
    const float* bi = (const float*)d_in[3];   // [3H]
    const float* bh = (const float*)d_in[4];   // [3H]
    const float* Wl = (const float*)d_in[5];   // [ID,H]
    const float* bl = (const float*)d_in[6];   // [ID]
    float* out = (float*)d_out;                // [B,T,ID]

    // workspace: hA, hB (1 MB each), y0 (128 KB), Bswz (1.7 MB bf16)
    float* hA = (float*)d_ws;
    float* hB = hA + (long)B * H;
    float* y0 = hB + (long)B * H;
    ushort* Bs = (ushort*)(y0 + (long)B * ID);

    init_kernel<<<2048, 256, 0, stream>>>(out, y0, hA, bl);
    prep_swizzle<<<(3 * 32 * NKT * 64 + 255) / 256, 256, 0, stream>>>(Wh, Wi, Bs);

    // ---- encoder ----
    const float* hin = hA;
    float* hout = hB;
    for (int t = 0; t < S; ++t) {
        gru_step_mfma<<<256, 256, 0, stream>>>(x + (long)t * ID, (long)S * ID,
                                               hin, Bs, bi, bh, hout);
        const float* tmp = hout; hout = (float*)hin; hin = tmp;
    }
    // hin == h_n

    // ---- y0 = h_n @ Wl.T + bl (bl pre-loaded by init) ----
    linear_y<<<B * 4, 64, 0, stream>>>(hin, Wl, y0, ID);

    // ---- decoder ----
    const float* inp = y0;
    long instride = ID;
    for (int t = 0; t < T; ++t) {
        gru_step_mfma<<<256, 256, 0, stream>>>(inp, instride,
                                               hin, Bs, bi, bh, hout);
        const float* tmp = hout; hout = (float*)hin; hin = tmp;
        // y_t = h @ Wl.T + bl -> straight into d_out slice t (pre-init'd to bl)
        linear_y<<<B * 4, 64, 0, stream>>>(hin, Wl, out + (long)t * ID, T * ID);
        inp = out + (long)t * ID;   // decoder feeds its own output back
        instride = T * ID;
    }
}